// Round 4
// baseline (795.872 us; speedup 1.0000x reference)
//
#include <hip/hip_runtime.h>
#include <hip/hip_bf16.h>

#define M_DIM 32768   // SEQ*BATCH
#define N_DIM 4096
#define K_DIM 1024

// ---- 256x256 tile, BK=64, 8 waves (2Mx4N), 512 threads, 2-buffer LDS ----
#define BM 256
#define BN 256
#define BK 64
#define NKT (K_DIM / BK)        // 16 K-tiles
#define NITER (NKT / 2)         // 8 iterations, 2 K-tiles each
#define TROWS (M_DIM / BM)      // 128
#define TCOLS (N_DIM / BN)      // 16
#define NWG (TROWS * TCOLS)     // 2048

typedef __attribute__((ext_vector_type(4))) float f32x4;
typedef __attribute__((ext_vector_type(8))) short bf16x8;

__device__ __forceinline__ unsigned short f2bf(float f) {
    unsigned int u = __float_as_uint(f);
    u += 0x7FFFu + ((u >> 16) & 1u);   // round-to-nearest-even
    return (unsigned short)(u >> 16);
}

__device__ __forceinline__ void gld_lds16(const void* gsrc, void* ldst) {
    __builtin_amdgcn_global_load_lds(
        (__attribute__((address_space(1))) void*)gsrc,
        (__attribute__((address_space(3))) void*)ldst,
        16, 0, 0);
}

// fp32 -> bf16 pre-cast of X and W into workspace (linear [row][k] layout).
__global__ void cast_kernel(const float* __restrict__ x, const float* __restrict__ w,
                            unsigned short* __restrict__ wsA, unsigned short* __restrict__ wsB) {
    const int nA = M_DIM * (K_DIM / 8);
    const int nB = N_DIM * (K_DIM / 8);
    const int total = nA + nB;
    const int stride = gridDim.x * blockDim.x;
    for (int i = blockIdx.x * blockDim.x + threadIdx.x; i < total; i += stride) {
        const float* src; unsigned short* dst; int g;
        if (i < nA) { src = x; dst = wsA; g = i; }
        else        { src = w; dst = wsB; g = i - nA; }
        const f32x4* s4 = (const f32x4*)(src + (size_t)g * 8);
        f32x4 v0 = s4[0];
        f32x4 v1 = s4[1];
        bf16x8 o;
        o[0] = (short)f2bf(v0[0]); o[1] = (short)f2bf(v0[1]);
        o[2] = (short)f2bf(v0[2]); o[3] = (short)f2bf(v0[3]);
        o[4] = (short)f2bf(v1[0]); o[5] = (short)f2bf(v1[1]);
        o[6] = (short)f2bf(v1[2]); o[7] = (short)f2bf(v1[3]);
        *(bf16x8*)(dst + (size_t)g * 8) = o;
    }
}

// ---- fences / waits ----
#define CFENCE() asm volatile("" ::: "memory")
#define BARR()   do { CFENCE(); __builtin_amdgcn_s_barrier(); CFENCE(); } while (0)
#define LGK0()   asm volatile("s_waitcnt lgkmcnt(0)" ::: "memory")
#define VM(n)    asm volatile("s_waitcnt vmcnt(" #n ")" ::: "memory")

#define MFMA_(a, b, c) __builtin_amdgcn_mfma_f32_16x16x32_bf16((a), (b), (c), 0, 0, 0)

// stage one half-tile (128 rows x BK cols bf16 = 16 KiB) = 2 gld_lds16/thread
#define STAGE_A(b, H, kt) do {                                                   \
    const unsigned short* _s = Abf + gA + (size_t)(H) * 128 * K_DIM + (kt) * BK; \
    unsigned char* _d = smem + (b) * 65536 + (H) * 16384 + (size_t)t * 16;       \
    gld_lds16(_s, _d);                                                           \
    gld_lds16(_s + 64 * K_DIM, _d + 8192);                                       \
} while (0)

#define STAGE_B(b, H, kt) do {                                                   \
    const unsigned short* _s = Bbf + gB + (size_t)(H) * 128 * K_DIM + (kt) * BK; \
    unsigned char* _d = smem + (b) * 65536 + 32768 + (H) * 16384 + (size_t)t * 16; \
    gld_lds16(_s, _d);                                                           \
    gld_lds16(_s + 64 * K_DIM, _d + 8192);                                       \
} while (0)

// read one A m-half (4 m-frags x 2 kk) / one B n-half (2 n-frags x 2 kk)
#define READ_A(DST, b, mh) do {                                                  \
    _Pragma("unroll")                                                            \
    for (int _m = 0; _m < 4; ++_m) {                                             \
        DST[_m][0] = *(const bf16x8*)(smem + (b) * 65536 + offA[(mh) * 4 + _m][0]); \
        DST[_m][1] = *(const bf16x8*)(smem + (b) * 65536 + offA[(mh) * 4 + _m][1]); \
    }                                                                            \
} while (0)

#define READ_B(DST, b, nh) do {                                                  \
    _Pragma("unroll")                                                            \
    for (int _n = 0; _n < 2; ++_n) {                                             \
        DST[_n][0] = *(const bf16x8*)(smem + (b) * 65536 + offB[(nh) * 2 + _n][0]); \
        DST[_n][1] = *(const bf16x8*)(smem + (b) * 65536 + offB[(nh) * 2 + _n][1]); \
    }                                                                            \
} while (0)

// one C-quadrant x K=64: 16 MFMA
#define MAC(A, B, mh, nh) do {                                                   \
    __builtin_amdgcn_s_setprio(1);                                               \
    _Pragma("unroll")                                                            \
    for (int _m = 0; _m < 4; ++_m)                                               \
        _Pragma("unroll")                                                        \
        for (int _n = 0; _n < 2; ++_n) {                                         \
            acc[(mh) * 4 + _m][(nh) * 2 + _n] =                                  \
                MFMA_(A[_m][0], B[_n][0], acc[(mh) * 4 + _m][(nh) * 2 + _n]);    \
            acc[(mh) * 4 + _m][(nh) * 2 + _n] =                                  \
                MFMA_(A[_m][1], B[_n][1], acc[(mh) * 4 + _m][(nh) * 2 + _n]);    \
        }                                                                        \
    __builtin_amdgcn_s_setprio(0);                                               \
} while (0)

// C = A(MxK) * B(NxK)^T + bias.  8-phase schedule (T3+T4+T5), 2 K-tiles per
// iteration.  Per phase: {ds_read next-phase frags | stage 1 half-tile |
// barrier | lgkmcnt(0) | 16 MFMA | [vmcnt(4)] barrier}.  vmcnt gates sit
// BEFORE a barrier so all waves' global_load_lds are visible to the reads
// that follow.  Liveness (verified by hand): every half-tile staged >=2
// phases before first read; every LDS region staged only after its last
// reader's barrier; no phase's ds_read targets regs used by its own MFMA.
__global__ __launch_bounds__(512, 2)
void gemm_kernel(const unsigned short* __restrict__ Abf,
                 const unsigned short* __restrict__ Bbf,
                 const float* __restrict__ bias, float* __restrict__ C) {
    __shared__ unsigned char smem[2 * 65536];   // buf b: A @ b*65536, B @ +32768

    const int t    = threadIdx.x;               // 0..511
    const int lane = t & 63;
    const int wave = t >> 6;
    const int wr   = wave >> 2;                 // 0..1 (M half)
    const int wc   = wave & 3;                  // 0..3 (N quarter)

    // XCD-aware mapping, per-XCD row-major (A-panel 512 KB reused 16x in L2)
    const int bid  = blockIdx.x;
    const int xcd  = bid & 7;
    const int jj   = bid >> 3;                  // 0..255
    const int row0 = (xcd * 16 + (jj >> 4)) * BM;
    const int col0 = (jj & 15) * BN;

    // ---- staging source (pre-swizzled global: jsrc = slot ^ (row&7)) ----
    const int rbase = t >> 3;                   // 0..63
    const int jsrc  = (t & 7) ^ (rbase & 7);
    const size_t gA = (size_t)(row0 + rbase) * K_DIM + jsrc * 8;
    const size_t gB = (size_t)(col0 + rbase) * K_DIM + jsrc * 8;

    // ---- ds_read offsets (swizzle re-applied on read) ----
    const int laneR = lane & 15;
    const int jb    = lane >> 4;                // k8-group 0..3
    int offA[8][2], offB[4][2];
    #pragma unroll
    for (int m = 0; m < 8; ++m) {
        const int r = wr * 128 + m * 16 + laneR;
        offA[m][0] = r * 128 + (((0 * 4 + jb) ^ (r & 7)) * 16);
        offA[m][1] = r * 128 + (((1 * 4 + jb) ^ (r & 7)) * 16);
    }
    #pragma unroll
    for (int n = 0; n < 4; ++n) {
        const int r = wc * 64 + n * 16 + laneR;
        offB[n][0] = 32768 + r * 128 + (((0 * 4 + jb) ^ (r & 7)) * 16);
        offB[n][1] = 32768 + r * 128 + (((1 * 4 + jb) ^ (r & 7)) * 16);
    }

    f32x4 acc[8][4] = {};
    bf16x8 As0[4][2], As1[4][2], Bs0[2][2], Bs1[2][2];

    // ---- prologue: K0 full -> buf0; K1 {Bh0, Ah0, Ah1} -> buf1 ----
    STAGE_B(0, 0, 0); STAGE_B(0, 1, 0); STAGE_A(0, 0, 0); STAGE_A(0, 1, 0);
    STAGE_B(1, 0, 1); STAGE_A(1, 0, 1); STAGE_A(1, 1, 1);
    VM(6);            // own K0 loads done (6 = K1's 3 half-tiles in flight)
    BARR();           // all waves' K0 loads visible
    READ_A(As0, 0, 0);
    READ_B(Bs0, 0, 0);

    // ---- main loop: iterations 0..NITER-2 (full staging) ----
    for (int it = 0; it < NITER - 1; ++it) {
        const int k1 = 2 * it + 1, k2 = 2 * it + 2, k3 = 2 * it + 3;
        // ph1: Kt0 (0,0)
        READ_B(Bs1, 0, 1); STAGE_B(1, 1, k1);
        BARR(); LGK0(); MAC(As0, Bs0, 0, 0); BARR();
        // ph2: Kt0 (0,1)
        READ_A(As1, 0, 1); STAGE_B(0, 0, k2);
        BARR(); LGK0(); MAC(As0, Bs1, 0, 1); VM(4); BARR();
        // ph3: Kt0 (1,1)
        READ_A(As0, 1, 0); STAGE_A(0, 0, k2);
        BARR(); LGK0(); MAC(As1, Bs1, 1, 1); VM(4); BARR();
        // ph4: Kt0 (1,0)
        READ_B(Bs1, 1, 1); STAGE_A(0, 1, k2);
        BARR(); LGK0(); MAC(As1, Bs0, 1, 0); BARR();
        // ph5: Kt1 (0,1)
        READ_B(Bs0, 1, 0); STAGE_B(0, 1, k2);
        BARR(); LGK0(); MAC(As0, Bs1, 0, 1); BARR();
        // ph6: Kt1 (0,0)
        READ_A(As1, 1, 1); STAGE_B(1, 0, k3);
        BARR(); LGK0(); MAC(As0, Bs0, 0, 0); VM(4); BARR();
        // ph7: Kt1 (1,0)
        READ_A(As0, 0, 0); STAGE_A(1, 0, k3);
        BARR(); LGK0(); MAC(As1, Bs0, 1, 0); VM(4); BARR();
        // ph8: Kt1 (1,1)
        READ_B(Bs0, 0, 0); STAGE_A(1, 1, k3);
        BARR(); LGK0(); MAC(As1, Bs1, 1, 1); BARR();
    }

    // ---- last iteration (kt0 = NKT-2, kt1 = NKT-1): no k2/k3 staging ----
    // ph1
    READ_B(Bs1, 0, 1); STAGE_B(1, 1, NKT - 1);
    BARR(); LGK0(); MAC(As0, Bs0, 0, 0); BARR();
    // ph2 (full drain once; nothing left in flight afterwards)
    READ_A(As1, 0, 1);
    BARR(); LGK0(); MAC(As0, Bs1, 0, 1); VM(0); BARR();
    // ph3
    READ_A(As0, 1, 0);
    BARR(); LGK0(); MAC(As1, Bs1, 1, 1); BARR();
    // ph4
    READ_B(Bs1, 1, 1);
    BARR(); LGK0(); MAC(As1, Bs0, 1, 0); BARR();
    // ph5
    READ_B(Bs0, 1, 0);
    BARR(); LGK0(); MAC(As0, Bs1, 0, 1); BARR();
    // ph6
    READ_A(As1, 1, 1);
    BARR(); LGK0(); MAC(As0, Bs0, 0, 0); BARR();
    // ph7
    LGK0(); MAC(As1, Bs0, 1, 0);
    // ph8
    MAC(As1, Bs1, 1, 1);

    // ---- C write: frag layout col = lane&15, row = (lane>>4)*4 + reg ----
    const int cr = (lane >> 4) * 4;
    const int cc = lane & 15;
    float bv[4];
    #pragma unroll
    for (int n = 0; n < 4; ++n)
        bv[n] = bias[col0 + wc * 64 + n * 16 + cc];
    #pragma unroll
    for (int m = 0; m < 8; ++m) {
        const int gr = row0 + wr * 128 + m * 16 + cr;
        #pragma unroll
        for (int n = 0; n < 4; ++n) {
            const int gc = col0 + wc * 64 + n * 16 + cc;
            float* p = C + (size_t)gr * N_DIM + gc;
            p[0]                 = acc[m][n][0] + bv[n];
            p[(size_t)N_DIM]     = acc[m][n][1] + bv[n];
            p[(size_t)2 * N_DIM] = acc[m][n][2] + bv[n];
            p[(size_t)3 * N_DIM] = acc[m][n][3] + bv[n];
        }
    }
}

// Fallback (no workspace): round-2 verified 128x128 fused-cast kernel.
__global__ __launch_bounds__(256, 4)
void gemm_fallback(const float* __restrict__ Af, const float* __restrict__ Bf,
                   const float* __restrict__ bias, float* __restrict__ C) {
    __shared__ unsigned char smem[32768];
    const int t = threadIdx.x, lane = t & 63, wave = t >> 6;
    const int wr = wave >> 1, wc = wave & 1;
    const int bid = blockIdx.x;
    const int swz = (bid & 7) * ((M_DIM / 128) * (N_DIM / 128) / 8) + (bid >> 3);
    const int row0 = (swz / (N_DIM / 128)) * 128;
    const int col0 = (swz % (N_DIM / 128)) * 128;
    const int srow = t >> 3;
    const int sj   = (t & 7) ^ (srow & 7);
    const int aoff0 = (row0 + srow) * K_DIM + sj * 8;
    const int boff0 = (col0 + srow) * K_DIM + sj * 8;
    f32x4 acc[4][4] = {};
    const int laneR = lane & 15, jb = lane >> 4, lx = lane & 7;
    f32x4 ra[4][2], rb[4][2];
    for (int kt = 0; kt < K_DIM / 64; ++kt) {
        const int kofs = kt * 64;
        #pragma unroll
        for (int i = 0; i < 4; ++i) {
            const float* pa = Af + aoff0 + i * (32 * K_DIM) + kofs;
            ra[i][0] = *(const f32x4*)pa; ra[i][1] = *(const f32x4*)(pa + 4);
            const float* pb = Bf + boff0 + i * (32 * K_DIM) + kofs;
            rb[i][0] = *(const f32x4*)pb; rb[i][1] = *(const f32x4*)(pb + 4);
        }
        #pragma unroll
        for (int i = 0; i < 4; ++i) {
            bf16x8 oa, ob;
            #pragma unroll
            for (int q = 0; q < 4; ++q) {
                oa[q] = (short)f2bf(ra[i][0][q]); oa[q + 4] = (short)f2bf(ra[i][1][q]);
                ob[q] = (short)f2bf(rb[i][0][q]); ob[q + 4] = (short)f2bf(rb[i][1][q]);
            }
            *(bf16x8*)(smem + i * 4096 + t * 16) = oa;
            *(bf16x8*)(smem + 16384 + i * 4096 + t * 16) = ob;
        }
        __syncthreads();
        #pragma unroll
        for (int kk = 0; kk < 2; ++kk) {
            bf16x8 af[4], bfr[4];
            #pragma unroll
            for (int m = 0; m < 4; ++m) {
                const int r = wr * 64 + m * 16 + laneR;
                af[m] = *(const bf16x8*)(smem + r * 128 + (((kk * 4 + jb) ^ lx) * 16));
            }
            #pragma unroll
            for (int n = 0; n < 4; ++n) {
                const int r = wc * 64 + n * 16 + laneR;
                bfr[n] = *(const bf16x8*)(smem + 16384 + r * 128 + (((kk * 4 + jb) ^ lx) * 16));
            }
            #pragma unroll
            for (int m = 0; m < 4; ++m)
                #pragma unroll
                for (int n = 0; n < 4; ++n)
                    acc[m][n] = __builtin_amdgcn_mfma_f32_16x16x32_bf16(
                        af[m], bfr[n], acc[m][n], 0, 0, 0);
        }
        __syncthreads();
    }
    const int cr = (lane >> 4) * 4, cc = lane & 15;
    float bv[4];
    #pragma unroll
    for (int n = 0; n < 4; ++n) bv[n] = bias[col0 + wc * 64 + n * 16 + cc];
    #pragma unroll
    for (int m = 0; m < 4; ++m) {
        const int gr = row0 + wr * 64 + m * 16 + cr;
        #pragma unroll
        for (int n = 0; n < 4; ++n) {
            const int gc = col0 + wc * 64 + n * 16 + cc;
            float* p = C + (size_t)gr * N_DIM + gc;
            p[0]                 = acc[m][n][0] + bv[n];
            p[(size_t)N_DIM]     = acc[m][n][1] + bv[n];
            p[(size_t)2 * N_DIM] = acc[m][n][2] + bv[n];
            p[(size_t)3 * N_DIM] = acc[m][n][3] + bv[n];
        }
    }
}

extern "C" void kernel_launch(void* const* d_in, const int* in_sizes, int n_in,
                              void* d_out, int out_size, void* d_ws, size_t ws_size,
                              hipStream_t stream) {
    const float* x    = (const float*)d_in[0];
    const float* w    = (const float*)d_in[1];
    const float* bias = (const float*)d_in[2];
    float* out        = (float*)d_out;

    const size_t needA = (size_t)M_DIM * K_DIM * sizeof(unsigned short);
    const size_t needB = (size_t)N_DIM * K_DIM * sizeof(unsigned short);

    if (ws_size >= needA + needB) {
        unsigned short* wsA = (unsigned short*)d_ws;
        unsigned short* wsB = wsA + (size_t)M_DIM * K_DIM;
        cast_kernel<<<4096, 256, 0, stream>>>(x, w, wsA, wsB);
        gemm_kernel<<<NWG, 512, 0, stream>>>(wsA, wsB, bias, out);
    } else {
        gemm_fallback<<<(M_DIM / 128) * (N_DIM / 128), 256, 0, stream>>>(x, w, bias, out);
    }
}

// Round 8
// 404.651 us; speedup vs baseline: 1.9668x; 1.9668x over previous
//
#include <hip/hip_runtime.h>
#include <hip/hip_bf16.h>

#define M_DIM 32768   // SEQ*BATCH
#define N_DIM 4096
#define K_DIM 1024

// ---- 256x256 tile, BK=32, 8 waves (2Mx4N), 512 threads, 3-buffer ring ----
#define BM 256
#define BN 256
#define BK 32
#define NKT (K_DIM / BK)        // 32 K-tiles (groups)
#define TROWS (M_DIM / BM)      // 128
#define TCOLS (N_DIM / BN)      // 16
#define NWG (TROWS * TCOLS)     // 2048
#define BUFB 32768              // per K-tile: A 16KB @0, B 16KB @16384

typedef __attribute__((ext_vector_type(4))) float f32x4;
typedef __attribute__((ext_vector_type(8))) short bf16x8;

__device__ __forceinline__ unsigned short f2bf(float f) {
    unsigned int u = __float_as_uint(f);
    u += 0x7FFFu + ((u >> 16) & 1u);   // round-to-nearest-even
    return (unsigned short)(u >> 16);
}

__device__ __forceinline__ void gld_lds16(const void* gsrc, void* ldst) {
    __builtin_amdgcn_global_load_lds(
        (__attribute__((address_space(1))) void*)gsrc,
        (__attribute__((address_space(3))) void*)ldst,
        16, 0, 0);
}

// fp32 -> bf16 pre-cast of X and W into workspace (linear [row][k] layout).
__global__ void cast_kernel(const float* __restrict__ x, const float* __restrict__ w,
                            unsigned short* __restrict__ wsA, unsigned short* __restrict__ wsB) {
    const int nA = M_DIM * (K_DIM / 8);
    const int nB = N_DIM * (K_DIM / 8);
    const int total = nA + nB;
    const int stride = gridDim.x * blockDim.x;
    for (int i = blockIdx.x * blockDim.x + threadIdx.x; i < total; i += stride) {
        const float* src; unsigned short* dst; int g;
        if (i < nA) { src = x; dst = wsA; g = i; }
        else        { src = w; dst = wsB; g = i - nA; }
        const f32x4* s4 = (const f32x4*)(src + (size_t)g * 8);
        f32x4 v0 = s4[0];
        f32x4 v1 = s4[1];
        bf16x8 o;
        o[0] = (short)f2bf(v0[0]); o[1] = (short)f2bf(v0[1]);
        o[2] = (short)f2bf(v0[2]); o[3] = (short)f2bf(v0[3]);
        o[4] = (short)f2bf(v1[0]); o[5] = (short)f2bf(v1[1]);
        o[6] = (short)f2bf(v1[2]); o[7] = (short)f2bf(v1[3]);
        *(bf16x8*)(dst + (size_t)g * 8) = o;
    }
}

// ---- fences / waits (rule #18: every wait/barrier followed by sched_barrier) ----
#define SCHED0() __builtin_amdgcn_sched_barrier(0)
#define CFENCE() asm volatile("" ::: "memory")
#define BARR()   do { CFENCE(); SCHED0(); __builtin_amdgcn_s_barrier(); \
                      SCHED0(); CFENCE(); } while (0)
#define LGK0()   do { asm volatile("s_waitcnt lgkmcnt(0)" ::: "memory"); SCHED0(); } while (0)
#define VM(n)    do { asm volatile("s_waitcnt vmcnt(" #n ")" ::: "memory"); SCHED0(); } while (0)

#define MFMA_(a, b, c) __builtin_amdgcn_mfma_f32_16x16x32_bf16((a), (b), (c), 0, 0, 0)

// stage one half (128 rows x 32 cols bf16 = 8KB) of A or B: 1 load/thread
#define STAGE_A(ST, H, kt) \
    gld_lds16(Abf + gA + (size_t)(H) * 128 * K_DIM + (kt) * BK, \
              smem + (ST) + (H) * 8192 + (size_t)t * 16)
#define STAGE_B(ST, H, kt) \
    gld_lds16(Bbf + gB + (size_t)(H) * 128 * K_DIM + (kt) * BK, \
              smem + (ST) + 16384 + (H) * 8192 + (size_t)t * 16)

// ds_read the A m-half (4 frags) / B n-half (2 frags); base runtime, rest imm
#define READ_A(AR, mh) do {                                              \
    _Pragma("unroll")                                                    \
    for (int _mm = 0; _mm < 4; ++_mm)                                    \
        Af[_mm] = *(const bf16x8*)(smem + (AR) + ((mh) * 4 + _mm) * 1024); \
} while (0)

#define READ_B(BR, nh) do {                                              \
    _Pragma("unroll")                                                    \
    for (int _nn = 0; _nn < 2; ++_nn)                                    \
        Bf[_nn] = *(const bf16x8*)(smem + (BR) + ((nh) * 2 + _nn) * 1024); \
} while (0)

// one C-quadrant x K=32: 8 MFMA
#define MAC(mh, nh) do {                                                 \
    __builtin_amdgcn_s_setprio(1);                                       \
    _Pragma("unroll")                                                    \
    for (int _mm = 0; _mm < 4; ++_mm)                                    \
        _Pragma("unroll")                                                \
        for (int _nn = 0; _nn < 2; ++_nn)                                \
            acc[(mh) * 4 + _mm][(nh) * 2 + _nn] =                        \
                MFMA_(Af[_mm], Bf[_nn], acc[(mh) * 4 + _mm][(nh) * 2 + _nn]); \
    __builtin_amdgcn_s_setprio(0);                                       \
} while (0)

// One K-tile group: read buf RD (tile t), stage tile kt=t+2 into buf ST.
// RD and ST are ALWAYS different ring buffers (t%3 vs (t+2)%3) -> staging
// can never overwrite data any wave still reads (round-7 root cause fixed
// structurally).  4 phases, quadrant snake (0,0)->(0,1)->(1,1)->(1,0),
// one closing barrier per phase; GATE4 at group end.
#define GROUP(RD, ST, kt, GATE4) do {                                    \
    const int aR = (RD) + aOff;                                          \
    const int bR = (RD) + bOff;                                          \
    READ_A(aR, 0); READ_B(bR, 0); STAGE_A(ST, 0, kt);                    \
    LGK0(); MAC(0, 0); BARR();                                           \
    READ_B(bR, 1);                STAGE_B(ST, 0, kt);                    \
    LGK0(); MAC(0, 1); BARR();                                           \
    READ_A(aR, 1);                STAGE_A(ST, 1, kt);                    \
    LGK0(); MAC(1, 1); BARR();                                           \
    READ_B(bR, 0);                STAGE_B(ST, 1, kt);                    \
    LGK0(); MAC(1, 0); GATE4; BARR();                                    \
} while (0)

#define GROUP_NS(RD, GATE4) do {                                         \
    const int aR = (RD) + aOff;                                          \
    const int bR = (RD) + bOff;                                          \
    READ_A(aR, 0); READ_B(bR, 0); LGK0(); MAC(0, 0); BARR();             \
    READ_B(bR, 1);                LGK0(); MAC(0, 1); BARR();             \
    READ_A(aR, 1);                LGK0(); MAC(1, 1); BARR();             \
    READ_B(bR, 0);                LGK0(); MAC(1, 0); GATE4;              \
} while (0)

#define NOGATE do {} while (0)

// C = A(MxK) * B(NxK)^T + bias.  3-ring counted-vmcnt pipeline:
// group t: { read buf t%3 | stage tile t+2 -> buf (t+2)%3 | VM(4) gate }.
// Invariant: entering group t exactly tile t+1's 4 loads are in flight;
// the gate retires them (issued >=4 phases earlier => latency covered)
// and keeps tile t+2's 4 in flight.  Never drains to 0 mid-loop (T4).
// LDS swizzle: slot ^= (row>>1)&3 (2-way max = free, round-3-verified),
// applied on pre-swizzled global source + on ds_read (both-sides rule).
__global__ __launch_bounds__(512, 2)
void gemm_kernel(const unsigned short* __restrict__ Abf,
                 const unsigned short* __restrict__ Bbf,
                 const float* __restrict__ bias, float* __restrict__ C) {
    __shared__ unsigned char smem[3 * BUFB];   // 96 KiB ring

    const int t    = threadIdx.x;               // 0..511
    const int lane = t & 63;
    const int wave = t >> 6;
    const int wr   = wave >> 2;                 // 0..1 (M half)
    const int wc   = wave & 3;                  // 0..3 (N quarter)

    // XCD-aware mapping, per-XCD row-major (A-panel reused 16x in L2)
    const int bid  = blockIdx.x;
    const int xcd  = bid & 7;
    const int jj   = bid >> 3;                  // 0..255
    const int row0 = (xcd * 16 + (jj >> 4)) * BM;
    const int col0 = (jj & 15) * BN;

    // ---- staging source (pre-swizzled global): LDS slot L = t within a
    // half: row = t>>2, s = t&3; content must be k8-group s ^ ((row>>1)&3)
    // = (t&3) ^ ((t>>3)&3).  Per-thread constant across halves/tiles. ----
    const int srow = t >> 2;                    // 0..127
    const int jsrc = (t & 3) ^ ((t >> 3) & 3);
    const size_t gA = (size_t)(row0 + srow) * K_DIM + jsrc * 8;
    const size_t gB = (size_t)(col0 + srow) * K_DIM + jsrc * 8;

    // ---- ds_read bases: (row>>1)&3 == (laneR>>1)&3 for all fragment rows
    // (m*16, wr*128, n*16, wc*64 are all multiples of 16) ----
    const int laneR = lane & 15;
    const int jb    = lane >> 4;                // k8-group 0..3
    const int slotR = (jb ^ ((laneR >> 1) & 3)) * 16;
    const int aOff  = wr * 8192 + laneR * 64 + slotR;
    const int bOff  = 16384 + wc * 4096 + laneR * 64 + slotR;

    f32x4  acc[8][4] = {};
    bf16x8 Af[4];   // current A m-half fragments
    bf16x8 Bf[2];   // current B n-half fragments

    // ---- prologue: tile0 -> buf0, tile1 -> buf1 (4 loads each) ----
    STAGE_A(0, 0, 0); STAGE_B(0, 0, 0); STAGE_A(0, 1, 0); STAGE_B(0, 1, 0);
    STAGE_A(BUFB, 0, 1); STAGE_B(BUFB, 0, 1); STAGE_A(BUFB, 1, 1); STAGE_B(BUFB, 1, 1);
    VM(4);      // retire tile0's 4; tile1's 4 stay in flight
    BARR();

    // ---- main loop: groups 0..26 (9 x 3, ring bases compile-time) ----
    for (int it = 0; it < 27; it += 3) {
        GROUP(0,        2 * BUFB, it + 2, VM(4));
        GROUP(BUFB,     0,        it + 3, VM(4));
        GROUP(2 * BUFB, BUFB,     it + 4, VM(4));
    }
    // groups 27..29 stage tiles 29..31
    GROUP(0,        2 * BUFB, 29, VM(4));
    GROUP(BUFB,     0,        30, VM(4));
    GROUP(2 * BUFB, BUFB,     31, VM(4));
    // group 30: no stage; full drain (retire tile31's 4)
    GROUP_NS(0, VM(0)); BARR();
    // group 31: no stage, no gate
    GROUP_NS(BUFB, NOGATE);

    // ---- epilogue: bias after all gates; C layout col=lane&15,
    // row=(lane>>4)*4+reg ----
    const int cr = (lane >> 4) * 4;
    const int cc = lane & 15;
    float bv[4];
    #pragma unroll
    for (int n = 0; n < 4; ++n)
        bv[n] = bias[col0 + wc * 64 + n * 16 + cc];
    #pragma unroll
    for (int m = 0; m < 8; ++m) {
        const int gr = row0 + wr * 128 + m * 16 + cr;
        #pragma unroll
        for (int n = 0; n < 4; ++n) {
            const int gc = col0 + wc * 64 + n * 16 + cc;
            float* p = C + (size_t)gr * N_DIM + gc;
            p[0]                 = acc[m][n][0] + bv[n];
            p[(size_t)N_DIM]     = acc[m][n][1] + bv[n];
            p[(size_t)2 * N_DIM] = acc[m][n][2] + bv[n];
            p[(size_t)3 * N_DIM] = acc[m][n][3] + bv[n];
        }
    }
}

// Fallback (no workspace): round-2 verified 128x128 fused-cast kernel.
__global__ __launch_bounds__(256, 4)
void gemm_fallback(const float* __restrict__ Af, const float* __restrict__ Bf,
                   const float* __restrict__ bias, float* __restrict__ C) {
    __shared__ unsigned char smem[32768];
    const int t = threadIdx.x, lane = t & 63, wave = t >> 6;
    const int wr = wave >> 1, wc = wave & 1;
    const int bid = blockIdx.x;
    const int swz = (bid & 7) * ((M_DIM / 128) * (N_DIM / 128) / 8) + (bid >> 3);
    const int row0 = (swz / (N_DIM / 128)) * 128;
    const int col0 = (swz % (N_DIM / 128)) * 128;
    const int srow = t >> 3;
    const int sj   = (t & 7) ^ (srow & 7);
    const int aoff0 = (row0 + srow) * K_DIM + sj * 8;
    const int boff0 = (col0 + srow) * K_DIM + sj * 8;
    f32x4 acc[4][4] = {};
    const int laneR = lane & 15, jb = lane >> 4, lx = lane & 7;
    f32x4 ra[4][2], rb[4][2];
    for (int kt = 0; kt < K_DIM / 64; ++kt) {
        const int kofs = kt * 64;
        #pragma unroll
        for (int i = 0; i < 4; ++i) {
            const float* pa = Af + aoff0 + i * (32 * K_DIM) + kofs;
            ra[i][0] = *(const f32x4*)pa; ra[i][1] = *(const f32x4*)(pa + 4);
            const float* pb = Bf + boff0 + i * (32 * K_DIM) + kofs;
            rb[i][0] = *(const f32x4*)pb; rb[i][1] = *(const f32x4*)(pb + 4);
        }
        #pragma unroll
        for (int i = 0; i < 4; ++i) {
            bf16x8 oa, ob;
            #pragma unroll
            for (int q = 0; q < 4; ++q) {
                oa[q] = (short)f2bf(ra[i][0][q]); oa[q + 4] = (short)f2bf(ra[i][1][q]);
                ob[q] = (short)f2bf(rb[i][0][q]); ob[q + 4] = (short)f2bf(rb[i][1][q]);
            }
            *(bf16x8*)(smem + i * 4096 + t * 16) = oa;
            *(bf16x8*)(smem + 16384 + i * 4096 + t * 16) = ob;
        }
        __syncthreads();
        #pragma unroll
        for (int kk = 0; kk < 2; ++kk) {
            bf16x8 af[4], bfr[4];
            #pragma unroll
            for (int m = 0; m < 4; ++m) {
                const int r = wr * 64 + m * 16 + laneR;
                af[m] = *(const bf16x8*)(smem + r * 128 + (((kk * 4 + jb) ^ lx) * 16));
            }
            #pragma unroll
            for (int n = 0; n < 4; ++n) {
                const int r = wc * 64 + n * 16 + laneR;
                bfr[n] = *(const bf16x8*)(smem + 16384 + r * 128 + (((kk * 4 + jb) ^ lx) * 16));
            }
            #pragma unroll
            for (int m = 0; m < 4; ++m)
                #pragma unroll
                for (int n = 0; n < 4; ++n)
                    acc[m][n] = __builtin_amdgcn_mfma_f32_16x16x32_bf16(
                        af[m], bfr[n], acc[m][n], 0, 0, 0);
        }
        __syncthreads();
    }
    const int cr = (lane >> 4) * 4, cc = lane & 15;
    float bv[4];
    #pragma unroll
    for (int n = 0; n < 4; ++n) bv[n] = bias[col0 + wc * 64 + n * 16 + cc];
    #pragma unroll
    for (int m = 0; m < 4; ++m) {
        const int gr = row0 + wr * 64 + m * 16 + cr;
        #pragma unroll
        for (int n = 0; n < 4; ++n) {
            const int gc = col0 + wc * 64 + n * 16 + cc;
            float* p = C + (size_t)gr * N_DIM + gc;
            p[0]                 = acc[m][n][0] + bv[n];
            p[(size_t)N_DIM]     = acc[m][n][1] + bv[n];
            p[(size_t)2 * N_DIM] = acc[m][n][2] + bv[n];
            p[(size_t)3 * N_DIM] = acc[m][n][3] + bv[n];
        }
    }
}

extern "C" void kernel_launch(void* const* d_in, const int* in_sizes, int n_in,
                              void* d_out, int out_size, void* d_ws, size_t ws_size,
                              hipStream_t stream) {
    const float* x    = (const float*)d_in[0];
    const float* w    = (const float*)d_in[1];
    const float* bias = (const float*)d_in[2];
    float* out        = (float*)d_out;

    const size_t needA = (size_t)M_DIM * K_DIM * sizeof(unsigned short);
    const size_t needB = (size_t)N_DIM * K_DIM * sizeof(unsigned short);

    if (ws_size >= needA + needB) {
        unsigned short* wsA = (unsigned short*)d_ws;
        unsigned short* wsB = wsA + (size_t)M_DIM * K_DIM;
        cast_kernel<<<4096, 256, 0, stream>>>(x, w, wsA, wsB);
        gemm_kernel<<<NWG, 512, 0, stream>>>(wsA, wsB, bias, out);
    } else {
        gemm_fallback<<<(M_DIM / 128) * (N_DIM / 128), 256, 0, stream>>>(x, w, bias, out);
    }
}